// Round 1
// baseline (44.717 us; speedup 1.0000x reference)
//
#include <hip/hip_runtime.h>

// DiversityLoss: attention_maps [B=64, M=32, H=128, W=128] fp32.
// gram[b,i,j] = sum_k (A[b,i,k]^2 * A[b,j,k]^2), K = 16384
// loss = mean_b( sum_{i<j} relu(0.1 - gram[b,i,j]) / 496 )
//
// Memory-bound: 134 MB read once -> ~21 us floor @6.3 TB/s.
// fp32 vector compute (no fp32 MFMA on CDNA4; 2.15 GFLOP << roofline).

#define MARGIN 0.1f

constexpr int B_ = 64;
constexpr int M_ = 32;
constexpr int K_ = 16384;
constexpr int NC = 16;            // K-chunks per batch
constexpr int KC = K_ / NC;       // 1024
constexpr int TS = 256;           // k-subtile staged in LDS
constexpr int NSUB = KC / TS;     // 4
constexpr int LSTRIDE = 36;       // dwords per k-row in LDS (32 + 4 pad) -> conflict-free b128 reads

// Kernel 1: per-(batch, chunk) partial Gram matrices.
// 256 threads = 4 waves; each wave handles a 64-k slice of the subtile;
// each lane computes a 4x4 tile of the 32x32 gram.
__global__ __launch_bounds__(256, 4) void gram_partial(const float* __restrict__ A,
                                                       float* __restrict__ ws_g) {
  __shared__ float lds[TS * LSTRIDE];  // 36 KiB

  const int tid  = threadIdx.x;
  const int lane = tid & 63;
  const int w    = tid >> 6;        // wave 0..3
  const int r    = tid >> 3;        // staging row 0..31
  const int j    = tid & 7;         // staging col-group 0..7
  const int lr   = lane >> 3;       // 0..7 (row tile)
  const int lc   = lane & 7;        // 0..7 (col tile)

  const int b = blockIdx.x >> 4;    // batch
  const int c = blockIdx.x & (NC - 1);

  const float4* A4 = reinterpret_cast<const float4*>(A);
  const size_t row_f4 = (size_t)(b * M_ + r) * (K_ / 4) + (size_t)c * (KC / 4);

  float acc[4][4];
#pragma unroll
  for (int p = 0; p < 4; ++p)
#pragma unroll
    for (int q = 0; q < 4; ++q) acc[p][q] = 0.0f;

  const float4* L4 = reinterpret_cast<const float4*>(lds);

  for (int s = 0; s < NSUB; ++s) {
    // Issue global loads early (overlap with previous subtile's compute tail).
    float4 v[8];
#pragma unroll
    for (int u = 0; u < 8; ++u) v[u] = A4[row_f4 + s * (TS / 4) + u * 8 + j];

    __syncthreads();  // prior subtile's LDS reads complete
#pragma unroll
    for (int u = 0; u < 8; ++u) {
      const int kl = u * 32 + j * 4;
      lds[(kl + 0) * LSTRIDE + r] = v[u].x * v[u].x;
      lds[(kl + 1) * LSTRIDE + r] = v[u].y * v[u].y;
      lds[(kl + 2) * LSTRIDE + r] = v[u].z * v[u].z;
      lds[(kl + 3) * LSTRIDE + r] = v[u].w * v[u].w;
    }
    __syncthreads();  // staged data visible

    const int kbase = w * 64;
#pragma unroll 4
    for (int kk = 0; kk < 64; ++kk) {
      const float4 av = L4[(kbase + kk) * (LSTRIDE / 4) + lr];
      const float4 bv = L4[(kbase + kk) * (LSTRIDE / 4) + lc];
      acc[0][0] = fmaf(av.x, bv.x, acc[0][0]);
      acc[0][1] = fmaf(av.x, bv.y, acc[0][1]);
      acc[0][2] = fmaf(av.x, bv.z, acc[0][2]);
      acc[0][3] = fmaf(av.x, bv.w, acc[0][3]);
      acc[1][0] = fmaf(av.y, bv.x, acc[1][0]);
      acc[1][1] = fmaf(av.y, bv.y, acc[1][1]);
      acc[1][2] = fmaf(av.y, bv.z, acc[1][2]);
      acc[1][3] = fmaf(av.y, bv.w, acc[1][3]);
      acc[2][0] = fmaf(av.z, bv.x, acc[2][0]);
      acc[2][1] = fmaf(av.z, bv.y, acc[2][1]);
      acc[2][2] = fmaf(av.z, bv.z, acc[2][2]);
      acc[2][3] = fmaf(av.z, bv.w, acc[2][3]);
      acc[3][0] = fmaf(av.w, bv.x, acc[3][0]);
      acc[3][1] = fmaf(av.w, bv.y, acc[3][1]);
      acc[3][2] = fmaf(av.w, bv.z, acc[3][2]);
      acc[3][3] = fmaf(av.w, bv.w, acc[3][3]);
    }
  }

  // Reduce the 4 per-wave partials (k-split) in LDS, then write 32x32 to ws.
  __syncthreads();
#pragma unroll
  for (int p = 0; p < 4; ++p)
#pragma unroll
    for (int q = 0; q < 4; ++q)
      lds[w * 1024 + (lr * 4 + p) * 32 + (lc * 4 + q)] = acc[p][q];
  __syncthreads();

  const int i0 = tid * 4;
  float4 o;
  o.x = lds[i0 + 0] + lds[1024 + i0 + 0] + lds[2048 + i0 + 0] + lds[3072 + i0 + 0];
  o.y = lds[i0 + 1] + lds[1024 + i0 + 1] + lds[2048 + i0 + 1] + lds[3072 + i0 + 1];
  o.z = lds[i0 + 2] + lds[1024 + i0 + 2] + lds[2048 + i0 + 2] + lds[3072 + i0 + 2];
  o.w = lds[i0 + 3] + lds[1024 + i0 + 3] + lds[2048 + i0 + 3] + lds[3072 + i0 + 3];
  reinterpret_cast<float4*>(ws_g)[(size_t)blockIdx.x * 256 + tid] = o;
}

// Kernel 2: per-batch -> sum chunk partials, relu margin, strict upper triangle.
__global__ __launch_bounds__(256) void reduce_batch(const float* __restrict__ ws_g,
                                                    float* __restrict__ ws_b) {
  const int b   = blockIdx.x;
  const int tid = threadIdx.x;
  const float4* G4 = reinterpret_cast<const float4*>(ws_g);

  float4 s = make_float4(0.f, 0.f, 0.f, 0.f);
  for (int c = 0; c < NC; ++c) {
    const float4 t = G4[((size_t)(b * NC + c)) * 256 + tid];
    s.x += t.x; s.y += t.y; s.z += t.z; s.w += t.w;
  }
  const float g[4] = {s.x, s.y, s.z, s.w};
  float local = 0.f;
#pragma unroll
  for (int e = 0; e < 4; ++e) {
    const int idx = tid * 4 + e;
    const int ii = idx >> 5;
    const int jj = idx & 31;
    if (jj > ii) local += fmaxf(MARGIN - g[e], 0.0f);
  }

  // block reduce (4 waves)
  float v = local;
#pragma unroll
  for (int off = 32; off > 0; off >>= 1) v += __shfl_down(v, off);
  __shared__ float red[4];
  if ((tid & 63) == 0) red[tid >> 6] = v;
  __syncthreads();
  if (tid == 0) ws_b[b] = (red[0] + red[1] + red[2] + red[3]) * (1.0f / 496.0f);
}

// Kernel 3: mean over batches.
__global__ void final_mean(const float* __restrict__ ws_b, float* __restrict__ out) {
  float v = ws_b[threadIdx.x];  // 64 threads
#pragma unroll
  for (int off = 32; off > 0; off >>= 1) v += __shfl_down(v, off);
  if (threadIdx.x == 0) out[0] = v * (1.0f / 64.0f);
}

extern "C" void kernel_launch(void* const* d_in, const int* in_sizes, int n_in,
                              void* d_out, int out_size, void* d_ws, size_t ws_size,
                              hipStream_t stream) {
  const float* A = reinterpret_cast<const float*>(d_in[0]);
  float* out = reinterpret_cast<float*>(d_out);

  // ws layout: [1024 blocks][1024 floats] partial grams (4 MiB) + [64] per-batch losses
  float* ws_g = reinterpret_cast<float*>(d_ws);
  float* ws_b = ws_g + (size_t)B_ * NC * M_ * M_;

  gram_partial<<<B_ * NC, 256, 0, stream>>>(A, ws_g);
  reduce_batch<<<B_, 256, 0, stream>>>(ws_g, ws_b);
  final_mean<<<1, 64, 0, stream>>>(ws_b, out);
}